// Round 2
// baseline (263.239 us; speedup 1.0000x reference)
//
#include <hip/hip_runtime.h>

#define TPB 256
#define PAIRS 4   // pixel-pairs per thread = 8 pixels/thread

typedef float f32x2 __attribute__((ext_vector_type(2)));
typedef float f32x4 __attribute__((ext_vector_type(4)));

__global__ __launch_bounds__(TPB) void uvtrans_kernel(
    const float* __restrict__ depth0,
    const float* __restrict__ R0,
    const float* __restrict__ t0,
    const float* __restrict__ R1,
    const float* __restrict__ t1,
    const float* __restrict__ K,
    const float* __restrict__ ray,
    float* __restrict__ out_uv,
    float* __restrict__ out_d,
    int N)
{
    const int b = blockIdx.y;

    // Wave-uniform (indexed by blockIdx.y) -> s_load into SGPRs.
    const float a00 = R0[b * 9 + 0], a01 = R0[b * 9 + 1], a02 = R0[b * 9 + 2];
    const float a10 = R0[b * 9 + 3], a11 = R0[b * 9 + 4], a12 = R0[b * 9 + 5];
    const float a20 = R0[b * 9 + 6], a21 = R0[b * 9 + 7], a22 = R0[b * 9 + 8];
    const float b00 = R1[b * 9 + 0], b01 = R1[b * 9 + 1], b02 = R1[b * 9 + 2];
    const float b10 = R1[b * 9 + 3], b11 = R1[b * 9 + 4], b12 = R1[b * 9 + 5];
    const float b20 = R1[b * 9 + 6], b21 = R1[b * 9 + 7], b22 = R1[b * 9 + 8];
    const float t00 = t0[b * 3 + 0], t01 = t0[b * 3 + 1], t02 = t0[b * 3 + 2];
    const float t10 = t1[b * 3 + 0], t11 = t1[b * 3 + 1], t12 = t1[b * 3 + 2];
    const float k00 = K[0], k01 = K[1], k02 = K[2];
    const float k10 = K[3], k11 = K[4], k12 = K[5];
    const float k20 = K[6], k21 = K[7], k22 = K[8];

    // Pixel-pair layout: every wave-level access is fully dense:
    //   depth: 8B/lane dwordx2, ray: 3x 8B/lane, uv: ONE 16B/lane dwordx4,
    //   d: 8B/lane dwordx2. PAIRS=4 chunks spaced 2*TPB pixels apart ->
    //   16 independent loads in flight per thread before any compute.
    const int span   = TPB * 2 * PAIRS;          // 2048 px per block
    const int base   = blockIdx.x * span;
    if (base >= N) return;
    const int n_lane = base + 2 * (int)threadIdx.x;

    if (base + span <= N) {
        // ---- fast path: whole block in range ----
        const size_t g0 = (size_t)b * N + n_lane;

        f32x2 dep[PAIRS];
        f32x2 ra[PAIRS], rb[PAIRS], rc[PAIRS];

        #pragma unroll
        for (int p = 0; p < PAIRS; ++p) {
            const size_t g = g0 + (size_t)p * (2 * TPB);
            // depth streamed once -> nontemporal; ray reused by 64 batches -> cached
            dep[p] = __builtin_nontemporal_load(
                reinterpret_cast<const f32x2*>(depth0 + g));
            const float* rp = ray + (size_t)(n_lane + p * (2 * TPB)) * 3;
            ra[p] = *reinterpret_cast<const f32x2*>(rp + 0);
            rb[p] = *reinterpret_cast<const f32x2*>(rp + 2);
            rc[p] = *reinterpret_cast<const f32x2*>(rp + 4);
        }

        #pragma unroll
        for (int p = 0; p < PAIRS; ++p) {
            const size_t g = g0 + (size_t)p * (2 * TPB);
            const float rays[6] = {ra[p].x, ra[p].y, rb[p].x, rb[p].y,
                                   rc[p].x, rc[p].y};
            const float deps[2] = {dep[p].x, dep[p].y};

            f32x4 uvv;
            f32x2 dvv;

            #pragma unroll
            for (int i = 0; i < 2; ++i) {
                const float dd = deps[i];
                // xyz = depth*ray - t0       (same op order as reference)
                const float p0 = fmaf(dd, rays[3 * i + 0], -t00);
                const float p1 = fmaf(dd, rays[3 * i + 1], -t01);
                const float p2 = fmaf(dd, rays[3 * i + 2], -t02);
                // y = xyz @ R0
                const float y0 = fmaf(p2, a20, fmaf(p1, a10, p0 * a00));
                const float y1 = fmaf(p2, a21, fmaf(p1, a11, p0 * a01));
                const float y2 = fmaf(p2, a22, fmaf(p1, a12, p0 * a02));
                // z = y @ R1^T + t1
                const float z0 = fmaf(y2, b02, fmaf(y1, b01, y0 * b00)) + t10;
                const float z1 = fmaf(y2, b12, fmaf(y1, b11, y0 * b10)) + t11;
                const float z2 = fmaf(y2, b22, fmaf(y1, b21, y0 * b20)) + t12;
                // uv3 = z @ K^T
                const float u0 = fmaf(z2, k02, fmaf(z1, k01, z0 * k00));
                const float u1 = fmaf(z2, k12, fmaf(z1, k11, z0 * k10));
                const float u2 = fmaf(z2, k22, fmaf(z1, k21, z0 * k20));

                const float denom = fmaxf(u2, 0.0f) + 1e-12f;
                float r = __builtin_amdgcn_rcpf(denom);
                r = r * fmaf(-denom, r, 2.0f);
                uvv[2 * i + 0] = u0 * r;
                uvv[2 * i + 1] = u1 * r;
                dvv[i] = u2;
            }

            __builtin_nontemporal_store(uvv,
                reinterpret_cast<f32x4*>(out_uv + g * 2));
            __builtin_nontemporal_store(dvv,
                reinterpret_cast<f32x2*>(out_d + g));
        }
    } else {
        // ---- tail path (not taken for N = 512*512) ----
        for (int p = 0; p < PAIRS; ++p) {
            const int n0 = n_lane + p * (2 * TPB);
            if (n0 + 2 > N) break;
            const size_t g = (size_t)b * N + n0;

            const f32x2 dep = __builtin_nontemporal_load(
                reinterpret_cast<const f32x2*>(depth0 + g));
            const float* rp = ray + (size_t)n0 * 3;
            const f32x2 ra0 = *reinterpret_cast<const f32x2*>(rp + 0);
            const f32x2 rb0 = *reinterpret_cast<const f32x2*>(rp + 2);
            const f32x2 rc0 = *reinterpret_cast<const f32x2*>(rp + 4);
            const float rays[6] = {ra0.x, ra0.y, rb0.x, rb0.y, rc0.x, rc0.y};
            const float deps[2] = {dep.x, dep.y};

            f32x4 uvv;
            f32x2 dvv;
            for (int i = 0; i < 2; ++i) {
                const float dd = deps[i];
                const float p0 = fmaf(dd, rays[3 * i + 0], -t00);
                const float p1 = fmaf(dd, rays[3 * i + 1], -t01);
                const float p2 = fmaf(dd, rays[3 * i + 2], -t02);
                const float y0 = fmaf(p2, a20, fmaf(p1, a10, p0 * a00));
                const float y1 = fmaf(p2, a21, fmaf(p1, a11, p0 * a01));
                const float y2 = fmaf(p2, a22, fmaf(p1, a12, p0 * a02));
                const float z0 = fmaf(y2, b02, fmaf(y1, b01, y0 * b00)) + t10;
                const float z1 = fmaf(y2, b12, fmaf(y1, b11, y0 * b10)) + t11;
                const float z2 = fmaf(y2, b22, fmaf(y1, b21, y0 * b20)) + t12;
                const float u0 = fmaf(z2, k02, fmaf(z1, k01, z0 * k00));
                const float u1 = fmaf(z2, k12, fmaf(z1, k11, z0 * k10));
                const float u2 = fmaf(z2, k22, fmaf(z1, k21, z0 * k20));
                const float denom = fmaxf(u2, 0.0f) + 1e-12f;
                float r = __builtin_amdgcn_rcpf(denom);
                r = r * fmaf(-denom, r, 2.0f);
                uvv[2 * i + 0] = u0 * r;
                uvv[2 * i + 1] = u1 * r;
                dvv[i] = u2;
            }
            __builtin_nontemporal_store(uvv,
                reinterpret_cast<f32x4*>(out_uv + g * 2));
            __builtin_nontemporal_store(dvv,
                reinterpret_cast<f32x2*>(out_d + g));
        }
    }
}

extern "C" void kernel_launch(void* const* d_in, const int* in_sizes, int n_in,
                              void* d_out, int out_size, void* d_ws, size_t ws_size,
                              hipStream_t stream) {
    const float* depth0 = (const float*)d_in[0];
    const float* R0     = (const float*)d_in[1];
    const float* t0     = (const float*)d_in[2];
    const float* R1     = (const float*)d_in[3];
    const float* t1     = (const float*)d_in[4];
    const float* K      = (const float*)d_in[5];
    const float* ray    = (const float*)d_in[6];

    const int N  = in_sizes[6] / 3;      // ray is (1, H*W, 3)
    const int BS = in_sizes[0] / N;      // depth0 is (BS, H, W)

    float* out    = (float*)d_out;
    float* out_uv = out;                             // (BS, N, 2) flat
    float* out_d  = out + (size_t)BS * N * 2;        // (BS, N, 1) flat

    const int px_per_block = TPB * 2 * PAIRS;        // 2048
    dim3 grid((N + px_per_block - 1) / px_per_block, BS);
    uvtrans_kernel<<<grid, TPB, 0, stream>>>(depth0, R0, t0, R1, t1, K, ray,
                                             out_uv, out_d, N);
}